// Round 3
// baseline (401.541 us; speedup 1.0000x reference)
//
#include <hip/hip_runtime.h>

#define NFEAT 2048
#define BATCH 16384
#define ROWS_PER_BLOCK 8
#define NBLOCKS (BATCH / ROWS_PER_BLOCK)   // 2048 blocks, barrier-free, long-lived

// out[i,j] = x[i, mask[i,j] ? perm[i,j] : j]
// x is read-only (out is a separate buffer), so no staging/barrier is needed:
// a direct global gather is correct. 90% of lanes use the identity index, so
// the gather is mostly-contiguous; random lanes hit L1/L2 (same-CU locality).
__global__ __launch_bounds__(256) void swap_corrupt_kernel(
    const float* __restrict__ x,
    const int*   __restrict__ mask,
    const int*   __restrict__ perm,
    float*       __restrict__ out)
{
    const int t = threadIdx.x;

    #pragma unroll 2
    for (int rr = 0; rr < ROWS_PER_BLOCK; ++rr) {
        const int r = blockIdx.x * ROWS_PER_BLOCK + rr;
        const size_t base = (size_t)r * NFEAT;

        const float* __restrict__ xr = x + base;
        const int4*  __restrict__ m4 = (const int4*)(mask + base);
        const int4*  __restrict__ p4 = (const int4*)(perm + base);
        float4*      __restrict__ o4 = (float4*)(out + base);

        // chunk 0: elements [4t .. 4t+3]
        {
            int4 m = m4[t];
            int4 p = p4[t];
            const int c0 = 4 * t;
            float4 o;
            o.x = xr[m.x ? p.x : c0];
            o.y = xr[m.y ? p.y : c0 + 1];
            o.z = xr[m.z ? p.z : c0 + 2];
            o.w = xr[m.w ? p.w : c0 + 3];
            o4[t] = o;
        }
        // chunk 1: elements [1024+4t .. 1024+4t+3]
        {
            int4 m = m4[t + 256];
            int4 p = p4[t + 256];
            const int c0 = 4 * (t + 256);
            float4 o;
            o.x = xr[m.x ? p.x : c0];
            o.y = xr[m.y ? p.y : c0 + 1];
            o.z = xr[m.z ? p.z : c0 + 2];
            o.w = xr[m.w ? p.w : c0 + 3];
            o4[t + 256] = o;
        }
    }
}

extern "C" void kernel_launch(void* const* d_in, const int* in_sizes, int n_in,
                              void* d_out, int out_size, void* d_ws, size_t ws_size,
                              hipStream_t stream) {
    const float* x    = (const float*)d_in[0];
    const int*   mask = (const int*)d_in[1];
    const int*   perm = (const int*)d_in[2];
    float*       out  = (float*)d_out;

    swap_corrupt_kernel<<<dim3(NBLOCKS), dim3(256), 0, stream>>>(x, mask, perm, out);
}